// Round 1
// baseline (537.921 us; speedup 1.0000x reference)
//
#include <hip/hip_runtime.h>
#include <cstdint>
#include <cstddef>

typedef _Float16 half8 __attribute__((ext_vector_type(8)));
typedef _Float16 half4 __attribute__((ext_vector_type(4)));
typedef float f32x4 __attribute__((ext_vector_type(4)));

#define GAT_N 8192
#define GAT_F 256
#define GAT_ALPHA 0.2f
#define GAT_LOG2E 1.4426950408889634f

// ---------------------------------------------------------------------------
// K1: Wh = h @ W in fp32 (no fp32 MFMA on CDNA4 -> vector ALU, LDS-tiled).
// Writes WhT (fp16, transposed [256][8192]) for MFMA B-operand use,
// plus f1 = Wh@a1, f2 = Wh@a2 in fp32.
// block: 32 rows x 256 cols, 256 threads; grid 256.
// ---------------------------------------------------------------------------
__global__ __launch_bounds__(256) void gat_k1_gemm(
    const float* __restrict__ h, const float* __restrict__ W,
    const float* __restrict__ a, _Float16* __restrict__ whT,
    float* __restrict__ f1, float* __restrict__ f2)
{
    __shared__ float sH[32][64];
    __shared__ float sW[64][256];
    const int tid = threadIdx.x;
    const int tx = tid & 31;       // col group
    const int ty = tid >> 5;       // 0..7, 4 rows each
    const int r0 = blockIdx.x * 32;

    float acc[4][8] = {};

    for (int kb = 0; kb < 256; kb += 64) {
        __syncthreads();
        for (int idx = tid; idx < 32 * 64; idx += 256) {
            int rr = idx >> 6, kk = idx & 63;
            sH[rr][kk] = h[(size_t)(r0 + rr) * 256 + kb + kk];
        }
        for (int idx = tid; idx < 64 * 256; idx += 256) {
            int rr = idx >> 8, cc = idx & 255;
            sW[rr][cc] = W[(size_t)(kb + rr) * 256 + cc];
        }
        __syncthreads();
        #pragma unroll 4
        for (int kk = 0; kk < 64; ++kk) {
            float av[4];
            #pragma unroll
            for (int i = 0; i < 4; ++i) av[i] = sH[ty * 4 + i][kk];
            #pragma unroll
            for (int j = 0; j < 8; ++j) {
                float bv = sW[kk][tx + 32 * j];
                #pragma unroll
                for (int i = 0; i < 4; ++i) acc[i][j] = fmaf(av[i], bv, acc[i][j]);
            }
        }
    }

    // f1/f2 partial dot with a1/a2 over this thread's 8 cols, reduce over tx.
    float p1[4] = {0.f, 0.f, 0.f, 0.f}, p2[4] = {0.f, 0.f, 0.f, 0.f};
    #pragma unroll
    for (int j = 0; j < 8; ++j) {
        float a1c = a[tx + 32 * j];
        float a2c = a[256 + tx + 32 * j];
        #pragma unroll
        for (int i = 0; i < 4; ++i) {
            p1[i] = fmaf(acc[i][j], a1c, p1[i]);
            p2[i] = fmaf(acc[i][j], a2c, p2[i]);
        }
    }
    #pragma unroll
    for (int off = 1; off < 32; off <<= 1) {
        #pragma unroll
        for (int i = 0; i < 4; ++i) {
            p1[i] += __shfl_xor(p1[i], off);
            p2[i] += __shfl_xor(p2[i], off);
        }
    }
    if (tx == 0) {
        #pragma unroll
        for (int i = 0; i < 4; ++i) {
            f1[r0 + ty * 4 + i] = p1[i];
            f2[r0 + ty * 4 + i] = p2[i];
        }
    }

    // WhT[c][r] fp16, packed 4 rows per 8B store.
    #pragma unroll
    for (int j = 0; j < 8; ++j) {
        half4 hv;
        #pragma unroll
        for (int i = 0; i < 4; ++i) hv[i] = (_Float16)acc[i][j];
        *reinterpret_cast<half4*>(whT + (size_t)(tx + 32 * j) * GAT_N + r0 + ty * 4) = hv;
    }
}

// ---------------------------------------------------------------------------
// K2: f2max = max_j f2[j]  (any upper bound works; softmax shift cancels)
// ---------------------------------------------------------------------------
__global__ __launch_bounds__(256) void gat_k2_max(
    const float* __restrict__ f2, float* __restrict__ f2mx)
{
    const int tid = threadIdx.x;
    float m = -3.0e38f;
    for (int i = tid; i < GAT_N; i += 256) m = fmaxf(m, f2[i]);
    #pragma unroll
    for (int off = 1; off < 64; off <<= 1) m = fmaxf(m, __shfl_xor(m, off));
    __shared__ float sm[4];
    if ((tid & 63) == 0) sm[tid >> 6] = m;
    __syncthreads();
    if (tid == 0) *f2mx = fmaxf(fmaxf(sm[0], sm[1]), fmaxf(sm[2], sm[3]));
}

// ---------------------------------------------------------------------------
// K3: fused masked softmax-numerator x V via fp16 MFMA. No LDS, no barriers.
// grid = 64 row-groups x 4 key-quarters. Block = 4 waves; wave owns 32 rows
// (two 16-row MFMA strips) x full 256 features, iterates its 2048-key slice.
// p = exp2(LOG2E*leaky(f1_i+f2_j) - C_i), C_i = LOG2E*leaky(f1_i+f2max);
// masked -> 0. Denominator accumulated per-lane in fp32 (A-layout fixes the
// row per lane). Partial numerators written per quarter; no normalization.
// ---------------------------------------------------------------------------
__global__ __launch_bounds__(256, 1) void gat_k3_attn(
    const int* __restrict__ adj, const float* __restrict__ f1,
    const float* __restrict__ f2, const float* __restrict__ f2mx,
    const _Float16* __restrict__ whT,
    float* __restrict__ P0, float* __restrict__ P1,
    float* __restrict__ P2, float* __restrict__ P3,
    float* __restrict__ L)  // [4][8192]
{
    const int bx = blockIdx.x;
    const int rb = bx >> 2;          // row group 0..63
    const int q  = bx & 3;           // key quarter
    const int wv = threadIdx.x >> 6;
    const int lane = threadIdx.x & 63;
    const int l15 = lane & 15;
    const int quad = lane >> 4;

    const int r0 = rb * 128 + wv * 32;
    const int rA = r0 + l15;         // strip 0 row (A-layout: row = lane&15)
    const int rB = r0 + 16 + l15;    // strip 1 row

    const float fmx = *f2mx;
    const float f1A = f1[rA];
    const float f1B = f1[rB];
    float sA = f1A + fmx;
    float sB = f1B + fmx;
    const float CA = GAT_LOG2E * (fmaxf(sA, 0.f) + GAT_ALPHA * fminf(sA, 0.f));
    const float CB = GAT_LOG2E * (fmaxf(sB, 0.f) + GAT_ALPHA * fminf(sB, 0.f));

    f32x4 acc[2][16];
    #pragma unroll
    for (int s = 0; s < 2; ++s)
        #pragma unroll
        for (int t = 0; t < 16; ++t) {
            f32x4 z = {0.f, 0.f, 0.f, 0.f};
            acc[s][t] = z;
        }
    float d0 = 0.f, d1 = 0.f;

    const int kq = q * 2048;
    const size_t rowA = (size_t)rA * GAT_N;
    const size_t rowB = (size_t)rB * GAT_N;
    const _Float16* wbase = whT + (size_t)l15 * GAT_N;

    #pragma unroll 2
    for (int step = 0; step < 64; ++step) {
        const int kb = kq + step * 32 + quad * 8;

        const int4 aA0 = *reinterpret_cast<const int4*>(adj + rowA + kb);
        const int4 aA1 = *reinterpret_cast<const int4*>(adj + rowA + kb + 4);
        const int4 aB0 = *reinterpret_cast<const int4*>(adj + rowB + kb);
        const int4 aB1 = *reinterpret_cast<const int4*>(adj + rowB + kb + 4);
        const float4 fa = *reinterpret_cast<const float4*>(f2 + kb);
        const float4 fb = *reinterpret_cast<const float4*>(f2 + kb + 4);

        const float f2v[8] = {fa.x, fa.y, fa.z, fa.w, fb.x, fb.y, fb.z, fb.w};
        const int am[8] = {aA0.x, aA0.y, aA0.z, aA0.w, aA1.x, aA1.y, aA1.z, aA1.w};
        const int bm[8] = {aB0.x, aB0.y, aB0.z, aB0.w, aB1.x, aB1.y, aB1.z, aB1.w};

        half8 pA, pB;
        #pragma unroll
        for (int j = 0; j < 8; ++j) {
            float f2j = f2v[j];
            float xa = f1A + f2j;
            float la = fmaxf(xa, 0.f) + GAT_ALPHA * fminf(xa, 0.f);
            float pa = __builtin_amdgcn_exp2f(fmaf(la, GAT_LOG2E, -CA));
            pa = (am[j] > 0) ? pa : 0.f;
            d0 += pa;
            pA[j] = (_Float16)pa;
            float xb = f1B + f2j;
            float lb = fmaxf(xb, 0.f) + GAT_ALPHA * fminf(xb, 0.f);
            float pb = __builtin_amdgcn_exp2f(fmaf(lb, GAT_LOG2E, -CB));
            pb = (bm[j] > 0) ? pb : 0.f;
            d1 += pb;
            pB[j] = (_Float16)pb;
        }

        #pragma unroll
        for (int t = 0; t < 16; ++t) {
            half8 bf = *reinterpret_cast<const half8*>(wbase + (size_t)t * 16 * GAT_N + kb);
            acc[0][t] = __builtin_amdgcn_mfma_f32_16x16x32_f16(pA, bf, acc[0][t], 0, 0, 0);
            acc[1][t] = __builtin_amdgcn_mfma_f32_16x16x32_f16(pB, bf, acc[1][t], 0, 0, 0);
        }
    }

    // Row denominators: reduce over the 4 quads (lanes l, l^16, l^32, l^48).
    d0 += __shfl_xor(d0, 16); d0 += __shfl_xor(d0, 32);
    d1 += __shfl_xor(d1, 16); d1 += __shfl_xor(d1, 32);
    float* Lq = L + q * GAT_N;
    if (lane < 16) { Lq[rA] = d0; Lq[rB] = d1; }

    // Store partial numerators. C-layout: col = lane&15, row = quad*4 + reg.
    float* const Ps[4] = {P0, P1, P2, P3};
    float* Pq = Ps[q];
    #pragma unroll
    for (int s = 0; s < 2; ++s) {
        const int rowbase = r0 + s * 16 + quad * 4;
        #pragma unroll
        for (int t = 0; t < 16; ++t) {
            const int col = t * 16 + l15;
            #pragma unroll
            for (int reg = 0; reg < 4; ++reg)
                Pq[(size_t)(rowbase + reg) * GAT_F + col] = acc[s][t][reg];
        }
    }
}

// ---------------------------------------------------------------------------
// K4: combine 4 partials, normalize by denominator, ELU. float4 vectorized.
// ---------------------------------------------------------------------------
__global__ __launch_bounds__(256) void gat_k4_final(
    float* __restrict__ out, const float* __restrict__ P1,
    const float* __restrict__ P2, const float* __restrict__ P3,
    const float* __restrict__ L)
{
    const size_t idx = (size_t)blockIdx.x * 256 + threadIdx.x;  // over 524288 float4
    const size_t row = idx >> 6;                                // 64 float4 per row
    float4 n = reinterpret_cast<float4*>(out)[idx];
    const float4 n1 = reinterpret_cast<const float4*>(P1)[idx];
    const float4 n2 = reinterpret_cast<const float4*>(P2)[idx];
    const float4 n3 = reinterpret_cast<const float4*>(P3)[idx];
    n.x += n1.x + n2.x + n3.x;
    n.y += n1.y + n2.y + n3.y;
    n.z += n1.z + n2.z + n3.z;
    n.w += n1.w + n2.w + n3.w;
    const float l = L[row] + L[GAT_N + row] + L[2 * GAT_N + row] + L[3 * GAT_N + row];
    const float rl = 1.0f / fmaxf(l, 1e-30f);
    float4 o;
    float v;
    v = n.x * rl; o.x = v > 0.f ? v : expm1f(v);
    v = n.y * rl; o.y = v > 0.f ? v : expm1f(v);
    v = n.z * rl; o.z = v > 0.f ? v : expm1f(v);
    v = n.w * rl; o.w = v > 0.f ? v : expm1f(v);
    reinterpret_cast<float4*>(out)[idx] = o;
}

// ---------------------------------------------------------------------------
extern "C" void kernel_launch(void* const* d_in, const int* in_sizes, int n_in,
                              void* d_out, int out_size, void* d_ws, size_t ws_size,
                              hipStream_t stream)
{
    const float* h   = (const float*)d_in[0];
    const int*   adj = (const int*)d_in[1];
    // d_in[2] = cv_values: constant per softmax row -> cancels exactly; unused.
    const float* W   = (const float*)d_in[3];
    const float* a   = (const float*)d_in[4];
    float* out = (float*)d_out;
    char* ws = (char*)d_ws;

    // ws layout (bytes):
    size_t off = 0;
    _Float16* whT = (_Float16*)(ws + off); off += (size_t)GAT_F * GAT_N * 2;   // 4 MB
    float* f1   = (float*)(ws + off); off += GAT_N * 4;                         // 32 KB
    float* f2   = (float*)(ws + off); off += GAT_N * 4;                         // 32 KB
    float* f2mx = (float*)(ws + off); off += 256;                               // pad
    float* P1   = (float*)(ws + off); off += (size_t)GAT_N * GAT_F * 4;         // 8 MB
    float* P2   = (float*)(ws + off); off += (size_t)GAT_N * GAT_F * 4;         // 8 MB
    float* P3   = (float*)(ws + off); off += (size_t)GAT_N * GAT_F * 4;         // 8 MB
    float* L    = (float*)(ws + off); off += 4 * GAT_N * 4;                     // 128 KB

    gat_k1_gemm<<<256, 256, 0, stream>>>(h, W, a, whT, f1, f2);
    gat_k2_max<<<1, 256, 0, stream>>>(f2, f2mx);
    gat_k3_attn<<<256, 256, 0, stream>>>(adj, f1, f2, f2mx, whT, out, P1, P2, P3, L);
    gat_k4_final<<<2048, 256, 0, stream>>>(out, P1, P2, P3, L);
}

// Round 2
// 502.056 us; speedup vs baseline: 1.0714x; 1.0714x over previous
//
#include <hip/hip_runtime.h>
#include <cstdint>
#include <cstddef>

typedef _Float16 half8 __attribute__((ext_vector_type(8)));
typedef _Float16 half4 __attribute__((ext_vector_type(4)));
typedef float f32x4 __attribute__((ext_vector_type(4)));

#define GAT_N 8192
#define GAT_F 256
#define GAT_ALPHA 0.2f
#define GAT_LOG2E 1.4426950408889634f

// Monotone float->uint encoding for atomicMax over floats of any sign.
__device__ inline unsigned enc_f32(float x) {
    unsigned b = __float_as_uint(x);
    return (b & 0x80000000u) ? ~b : (b | 0x80000000u);
}
__device__ inline float dec_f32(unsigned u) {
    unsigned b = (u & 0x80000000u) ? (u ^ 0x80000000u) : ~u;
    return __uint_as_float(b);
}

// ---------------------------------------------------------------------------
// K0: convert h -> fp16 (row-major), W -> fp16 transposed WT[n][k];
// init encoded f2max to -inf.
// ---------------------------------------------------------------------------
__global__ __launch_bounds__(256) void gat_k0_convert(
    const float* __restrict__ h, const float* __restrict__ W,
    _Float16* __restrict__ h16, _Float16* __restrict__ WT,
    unsigned* __restrict__ f2mxEnc)
{
    const int gtid = blockIdx.x * 256 + threadIdx.x;   // 131072 threads
    if (gtid == 0) *f2mxEnc = 0u;                       // enc(-FLT_MAX)
    // h: 2,097,152 floats = 524,288 float4
    for (int i = gtid; i < (GAT_N * GAT_F / 4); i += 131072) {
        float4 v = reinterpret_cast<const float4*>(h)[i];
        half4 o; o[0] = (_Float16)v.x; o[1] = (_Float16)v.y;
        o[2] = (_Float16)v.z; o[3] = (_Float16)v.w;
        reinterpret_cast<half4*>(h16)[i] = o;
    }
    // W: 65536 elements, transpose
    if (gtid < GAT_F * GAT_F) {
        int k = gtid >> 8, n = gtid & 255;
        WT[n * GAT_F + k] = (_Float16)W[gtid];
    }
}

// ---------------------------------------------------------------------------
// K1: Wh = h @ W via fp16 MFMA (fp32 accum). Each wave: 16 rows x 256 cols.
// Epilogue: f1 = Wh@a1, f2 = Wh@a2 (fp32, from fp32 accumulators),
// atomicMax of encoded f2 -> f2mxEnc, and whT[n][row] fp16 store.
// grid 128 blocks x 4 waves (64 rows/block).
// ---------------------------------------------------------------------------
__global__ __launch_bounds__(256) void gat_k1_gemm(
    const _Float16* __restrict__ h16, const _Float16* __restrict__ WT,
    const float* __restrict__ a, _Float16* __restrict__ whT,
    float* __restrict__ f1, float* __restrict__ f2,
    unsigned* __restrict__ f2mxEnc)
{
    const int wv = threadIdx.x >> 6;
    const int lane = threadIdx.x & 63;
    const int l15 = lane & 15;
    const int quad = lane >> 4;
    const int r0 = blockIdx.x * 64 + wv * 16;

    f32x4 acc[16];
    #pragma unroll
    for (int t = 0; t < 16; ++t) { f32x4 z = {0.f,0.f,0.f,0.f}; acc[t] = z; }

    #pragma unroll
    for (int k0 = 0; k0 < GAT_F; k0 += 32) {
        half8 af = *reinterpret_cast<const half8*>(
            h16 + (size_t)(r0 + l15) * GAT_F + k0 + quad * 8);
        #pragma unroll
        for (int t = 0; t < 16; ++t) {
            half8 bf = *reinterpret_cast<const half8*>(
                WT + (size_t)(t * 16 + l15) * GAT_F + k0 + quad * 8);
            acc[t] = __builtin_amdgcn_mfma_f32_16x16x32_f16(af, bf, acc[t], 0, 0, 0);
        }
    }

    // f1/f2 epilogue. Lane holds rows quad*4+reg, cols t*16+l15.
    float p1[4] = {0.f,0.f,0.f,0.f}, p2[4] = {0.f,0.f,0.f,0.f};
    #pragma unroll
    for (int t = 0; t < 16; ++t) {
        float a1c = a[t * 16 + l15];
        float a2c = a[GAT_F + t * 16 + l15];
        #pragma unroll
        for (int r = 0; r < 4; ++r) {
            p1[r] = fmaf(acc[t][r], a1c, p1[r]);
            p2[r] = fmaf(acc[t][r], a2c, p2[r]);
        }
    }
    #pragma unroll
    for (int off = 1; off < 16; off <<= 1) {
        #pragma unroll
        for (int r = 0; r < 4; ++r) {
            p1[r] += __shfl_xor(p1[r], off);
            p2[r] += __shfl_xor(p2[r], off);
        }
    }
    if (l15 == 0) {
        float mx = -3.0e38f;
        #pragma unroll
        for (int r = 0; r < 4; ++r) {
            int row = r0 + quad * 4 + r;
            f1[row] = p1[r];
            f2[row] = p2[r];
            mx = fmaxf(mx, p2[r]);
        }
        atomicMax(f2mxEnc, enc_f32(mx));
    }

    // whT[n][row] fp16: lane stores 4 consecutive rows per col-tile.
    #pragma unroll
    for (int t = 0; t < 16; ++t) {
        half4 hv;
        #pragma unroll
        for (int r = 0; r < 4; ++r) hv[r] = (_Float16)acc[t][r];
        *reinterpret_cast<half4*>(
            whT + (size_t)(t * 16 + l15) * GAT_N + r0 + quad * 4) = hv;
    }
}

// ---------------------------------------------------------------------------
// K3: fused masked softmax-numerator x V via fp16 MFMA.
// grid = 64 row-groups x 8 key-slices = 512 blocks (2 blocks/CU, 2 waves/SIMD).
// Wave: 32 rows (2 strips) x 256 feats, 1024-key slice (32 steps of 32 keys).
// Explicit register prefetch of next step's adj/f2. Partials stored fp16 in
// MFMA C-layout permuted order -> perfectly coalesced half4 stores.
// ---------------------------------------------------------------------------
__global__ __launch_bounds__(256, 2) void gat_k3_attn(
    const int* __restrict__ adj, const float* __restrict__ f1,
    const float* __restrict__ f2, const unsigned* __restrict__ f2mxEnc,
    const _Float16* __restrict__ whT,
    _Float16* __restrict__ Ph,     // 8 slabs x 8192x256 fp16, permuted
    float* __restrict__ L)         // [8][8192]
{
    const int bx = blockIdx.x;
    const int rb = bx >> 3;          // row group 0..63
    const int q  = bx & 7;           // key slice 0..7 (bx%8 ~ XCD -> L2 reuse)
    const int wv = threadIdx.x >> 6;
    const int lane = threadIdx.x & 63;
    const int l15 = lane & 15;
    const int quad = lane >> 4;

    const int r0 = rb * 128 + wv * 32;
    const int rA = r0 + l15;
    const int rB = r0 + 16 + l15;

    const float fmx = dec_f32(*f2mxEnc);
    const float f1A = f1[rA];
    const float f1B = f1[rB];
    const float sA = f1A + fmx;
    const float sB = f1B + fmx;
    const float CA = GAT_LOG2E * (fmaxf(sA, 0.f) + GAT_ALPHA * fminf(sA, 0.f));
    const float CB = GAT_LOG2E * (fmaxf(sB, 0.f) + GAT_ALPHA * fminf(sB, 0.f));

    f32x4 acc[2][16];
    #pragma unroll
    for (int s = 0; s < 2; ++s)
        #pragma unroll
        for (int t = 0; t < 16; ++t) {
            f32x4 z = {0.f,0.f,0.f,0.f};
            acc[s][t] = z;
        }
    float d0 = 0.f, d1 = 0.f;

    const int kq = q * 1024;
    const size_t rowA = (size_t)rA * GAT_N;
    const size_t rowB = (size_t)rB * GAT_N;
    const _Float16* wbase = whT + (size_t)l15 * GAT_N;

    // prefetch registers (next step)
    int kb0 = kq + quad * 8;
    int4 nA0 = *reinterpret_cast<const int4*>(adj + rowA + kb0);
    int4 nA1 = *reinterpret_cast<const int4*>(adj + rowA + kb0 + 4);
    int4 nB0 = *reinterpret_cast<const int4*>(adj + rowB + kb0);
    int4 nB1 = *reinterpret_cast<const int4*>(adj + rowB + kb0 + 4);
    float4 nfa = *reinterpret_cast<const float4*>(f2 + kb0);
    float4 nfb = *reinterpret_cast<const float4*>(f2 + kb0 + 4);

    #pragma unroll 2
    for (int step = 0; step < 32; ++step) {
        const int4 cA0 = nA0, cA1 = nA1, cB0 = nB0, cB1 = nB1;
        const float4 cfa = nfa, cfb = nfb;
        if (step < 31) {
            const int kbn = kq + (step + 1) * 32 + quad * 8;
            nA0 = *reinterpret_cast<const int4*>(adj + rowA + kbn);
            nA1 = *reinterpret_cast<const int4*>(adj + rowA + kbn + 4);
            nB0 = *reinterpret_cast<const int4*>(adj + rowB + kbn);
            nB1 = *reinterpret_cast<const int4*>(adj + rowB + kbn + 4);
            nfa = *reinterpret_cast<const float4*>(f2 + kbn);
            nfb = *reinterpret_cast<const float4*>(f2 + kbn + 4);
        }

        const float f2v[8] = {cfa.x, cfa.y, cfa.z, cfa.w, cfb.x, cfb.y, cfb.z, cfb.w};
        const int am[8] = {cA0.x, cA0.y, cA0.z, cA0.w, cA1.x, cA1.y, cA1.z, cA1.w};
        const int bm[8] = {cB0.x, cB0.y, cB0.z, cB0.w, cB1.x, cB1.y, cB1.z, cB1.w};

        half8 pA, pB;
        #pragma unroll
        for (int j = 0; j < 8; ++j) {
            float f2j = f2v[j];
            float xa = f1A + f2j;
            float la = fmaxf(xa, 0.f) + GAT_ALPHA * fminf(xa, 0.f);
            float pa = __builtin_amdgcn_exp2f(fmaf(la, GAT_LOG2E, -CA));
            pa = (am[j] > 0) ? pa : 0.f;
            d0 += pa;
            pA[j] = (_Float16)pa;
            float xb = f1B + f2j;
            float lb = fmaxf(xb, 0.f) + GAT_ALPHA * fminf(xb, 0.f);
            float pb = __builtin_amdgcn_exp2f(fmaf(lb, GAT_LOG2E, -CB));
            pb = (bm[j] > 0) ? pb : 0.f;
            d1 += pb;
            pB[j] = (_Float16)pb;
        }

        const int kb = kq + step * 32 + quad * 8;
        #pragma unroll
        for (int t = 0; t < 16; ++t) {
            half8 bf = *reinterpret_cast<const half8*>(
                wbase + (size_t)t * 16 * GAT_N + kb);
            acc[0][t] = __builtin_amdgcn_mfma_f32_16x16x32_f16(pA, bf, acc[0][t], 0, 0, 0);
            acc[1][t] = __builtin_amdgcn_mfma_f32_16x16x32_f16(pB, bf, acc[1][t], 0, 0, 0);
        }
    }

    // Row denominators: reduce over quads (all lanes end with full row sum).
    d0 += __shfl_xor(d0, 16); d0 += __shfl_xor(d0, 32);
    d1 += __shfl_xor(d1, 16); d1 += __shfl_xor(d1, 32);
    float* Lq = L + q * GAT_N;
    if (lane < 16) { Lq[rA] = d0; Lq[rB] = d1; }

    // Coalesced permuted fp16 partial store: wave-chunk of 8192 halves.
    const int wid = rb * 4 + wv;                       // 0..255
    _Float16* Pq = Ph + ((size_t)q * 256 + wid) * 8192;
    #pragma unroll
    for (int s = 0; s < 2; ++s)
        #pragma unroll
        for (int t = 0; t < 16; ++t) {
            half4 hv;
            #pragma unroll
            for (int r = 0; r < 4; ++r) hv[r] = (_Float16)acc[s][t][r];
            *reinterpret_cast<half4*>(Pq + (size_t)(((s * 16 + t) * 64 + lane) * 4)) = hv;
        }
}

// ---------------------------------------------------------------------------
// K4: un-permute + combine 8 fp16 partials, normalize, ELU, write out.
// One block handles 256 half4 positions of one wave-chunk (8 blocks/chunk).
// ---------------------------------------------------------------------------
__global__ __launch_bounds__(256) void gat_k4_final(
    const _Float16* __restrict__ Ph, const float* __restrict__ L,
    float* __restrict__ out)
{
    const int tid = threadIdx.x;
    const int wid = blockIdx.x >> 3;                   // wave-chunk 0..255
    __shared__ float s_rl[32];
    if (tid < 32) {
        const int row = wid * 32 + tid;
        float s = 0.f;
        #pragma unroll
        for (int q = 0; q < 8; ++q) s += L[q * GAT_N + row];
        s_rl[tid] = 1.0f / fmaxf(s, 1e-30f);
    }
    __syncthreads();

    const int idx = blockIdx.x * 256 + tid;            // half4 position
    const int rem = idx & 2047;                        // within wave-chunk
    const int lane = rem & 63;
    const int st = rem >> 6;
    const int s = st >> 4, t = st & 15;
    const int l15 = lane & 15, quad = lane >> 4;
    const int lrow0 = s * 16 + quad * 4;               // local rows lrow0..+3
    const int col = t * 16 + l15;

    float accv[4] = {0.f, 0.f, 0.f, 0.f};
    #pragma unroll
    for (int q = 0; q < 8; ++q) {
        half4 v = *reinterpret_cast<const half4*>(
            Ph + ((size_t)q * 256 + wid) * 8192 + (size_t)rem * 4);
        #pragma unroll
        for (int r = 0; r < 4; ++r) accv[r] += (float)v[r];
    }
    #pragma unroll
    for (int r = 0; r < 4; ++r) {
        const float v = accv[r] * s_rl[lrow0 + r];
        const float o = v > 0.f ? v : expm1f(v);
        out[(size_t)(wid * 32 + lrow0 + r) * GAT_F + col] = o;
    }
}

// ---------------------------------------------------------------------------
extern "C" void kernel_launch(void* const* d_in, const int* in_sizes, int n_in,
                              void* d_out, int out_size, void* d_ws, size_t ws_size,
                              hipStream_t stream)
{
    const float* h   = (const float*)d_in[0];
    const int*   adj = (const int*)d_in[1];
    // d_in[2] = cv_values: constant per softmax row -> cancels exactly; unused.
    const float* W   = (const float*)d_in[3];
    const float* a   = (const float*)d_in[4];
    float* out = (float*)d_out;
    char* ws = (char*)d_ws;

    const size_t SLAB = (size_t)GAT_N * GAT_F * 2;     // 4 MiB (fp16 matrix)

    // ws layout: whT | Ph[8 slabs] | f1 f2 L f2mx.
    // h16 aliases Ph slab 0, WT aliases Ph slab 1 (dead after K1; K3 writes Ph).
    _Float16* whT = (_Float16*)(ws);
    _Float16* Ph  = (_Float16*)(ws + SLAB);
    _Float16* h16 = Ph;                                 // alias slab 0
    _Float16* WT  = Ph + (SLAB / 2);                    // alias slab 1 start
    char* tail = ws + SLAB + 8 * SLAB;
    float* f1 = (float*)(tail);
    float* f2 = (float*)(tail + GAT_N * 4);
    float* L  = (float*)(tail + 2 * GAT_N * 4);
    unsigned* f2mxEnc = (unsigned*)(tail + 2 * GAT_N * 4 + 8 * GAT_N * 4);

    gat_k0_convert<<<512, 256, 0, stream>>>(h, W, h16, WT, f2mxEnc);
    gat_k1_gemm<<<128, 256, 0, stream>>>(h16, WT, a, whT, f1, f2, f2mxEnc);
    gat_k3_attn<<<512, 256, 0, stream>>>(adj, f1, f2, f2mxEnc, whT, Ph, L);
    gat_k4_final<<<2048, 256, 0, stream>>>(Ph, L, out);
}